// Round 3
// baseline (137.330 us; speedup 1.0000x reference)
//
#include <hip/hip_runtime.h>
#include <math.h>

#define HW 384
#define PLANE (HW*HW)   // 147456

// ---- workspace layout (float-index offsets) ----
#define WT1_OFF   0                         // 7200 floats: [c*25+tap][32 o]
#define SC1_OFF   7296                      // 32
#define SH1_OFF   7328                      // 32
#define WT2_OFF   7360                      // 6400: [ci*25+tap][8 o]
#define SC2_OFF   13760                     // 8
#define SH2_OFF   13768                     // 8
#define W3_OFF    13776                     // 200: [ci*25+tap]
#define SC3_OFF   13976                     // 1
#define SH3_OFF   13977                     // 1
#define FWT_OFF   13984                     // 5488: [(dz*7+dy)*7+dx][c*4+o]
#define H1_OFF    32768                     // 32*PLANE
#define H2_OFF    (32768 + 32*PLANE)        // 8*PLANE
#define DEPTH_OFF (32768 + 40*PLANE)        // PLANE int32

// ---------------- prep: fold BN, transpose weights (multi-block) ----------------
__global__ void prep_kernel(
    const float* __restrict__ c1w, const float* __restrict__ c1b,
    const float* __restrict__ g1, const float* __restrict__ b1,
    const float* __restrict__ m1, const float* __restrict__ v1,
    const float* __restrict__ c2w, const float* __restrict__ c2b,
    const float* __restrict__ g2, const float* __restrict__ b2,
    const float* __restrict__ m2, const float* __restrict__ v2,
    const float* __restrict__ c3w, const float* __restrict__ c3b,
    const float* __restrict__ g3, const float* __restrict__ b3,
    const float* __restrict__ m3, const float* __restrict__ v3,
    const float* __restrict__ fw, float* __restrict__ W)
{
    int gid = blockIdx.x * 256 + threadIdx.x;
    int gstr = gridDim.x * 256;
    for (int i = gid; i < 7200; i += gstr) {
        int o = i & 31, ct = i >> 5;
        W[WT1_OFF + i] = c1w[o * 225 + ct];
    }
    for (int i = gid; i < 6400; i += gstr) {
        int o = i & 7, ct = i >> 3;
        W[WT2_OFF + i] = c2w[o * 800 + ct];
    }
    for (int i = gid; i < 5488; i += gstr) {
        int s = i >> 4, r = i & 15, c = r >> 2, o = r & 3;
        W[FWT_OFF + i] = fw[o * 1372 + c * 343 + s];
    }
    if (blockIdx.x == 0) {
        int tid = threadIdx.x;
        if (tid < 32) {
            float sc = g1[tid] / sqrtf(v1[tid] + 1e-5f);
            W[SC1_OFF + tid] = sc;
            W[SH1_OFF + tid] = (c1b[tid] - m1[tid]) * sc + b1[tid];
        }
        if (tid < 8) {
            float sc = g2[tid] / sqrtf(v2[tid] + 1e-5f);
            W[SC2_OFF + tid] = sc;
            W[SH2_OFF + tid] = (c2b[tid] - m2[tid]) * sc + b2[tid];
        }
        if (tid < 200) W[W3_OFF + tid] = c3w[tid];
        if (tid == 0) {
            float sc = g3[0] / sqrtf(v3[0] + 1e-5f);
            W[SC3_OFF] = sc;
            W[SH3_OFF] = (c3b[0] - m3[0]) * sc + b3[0];
        }
    }
}

// ---------------- conv1: 9 -> 32, 5x5, BN+ReLU ----------------
// 256 thr = 64 pixel-quad slots x 4 output-channel groups of 8.
// Each thread computes 4 adjacent x-pixels via 2x ds_read_b128 per (c,ky) row.
__global__ __launch_bounds__(256, 2) void conv1_kernel(
    const float* __restrict__ light, const float* __restrict__ albedo,
    const float* __restrict__ normals, const float* __restrict__ W,
    float* __restrict__ h1)
{
    __shared__ __align__(16) float tile[9][12][36];
    int tid = threadIdx.x;
    int og = tid >> 6;            // output group 0..3 (= wave id)
    int slot = tid & 63;
    int qx = slot & 7, ty = slot >> 3;
    int bx = blockIdx.x % 12, by = blockIdx.x / 12;
    int x0 = bx * 32 - 2, y0 = by * 8 - 2;

    for (int p = tid; p < 432; p += 256) {
        int py = p / 36, px = p % 36;
        int gy = y0 + py, gx = x0 + px;
        bool ok = ((unsigned)gy < (unsigned)HW) && ((unsigned)gx < (unsigned)HW);
        int gofs = ok ? (gy * HW + gx) : 0;
#pragma unroll
        for (int c = 0; c < 3; ++c) {
            float a = light[c * PLANE + gofs];
            float b = albedo[c * PLANE + gofs];
            float n = normals[c * PLANE + gofs];
            tile[c][py][px]     = ok ? a : 0.f;
            tile[c + 3][py][px] = ok ? b : 0.f;
            tile[c + 6][py][px] = ok ? n : 0.f;
        }
    }
    __syncthreads();

    float acc[8][4];
#pragma unroll
    for (int o = 0; o < 8; ++o)
#pragma unroll
        for (int j = 0; j < 4; ++j) acc[o][j] = 0.f;

    const float* wb = W + WT1_OFF + og * 8;   // [ct][32o], take 8 outs
#pragma unroll 1
    for (int c = 0; c < 9; ++c) {
        const float* bc = &tile[c][0][0];
        const float* wc = wb + c * 25 * 32;
#pragma unroll
        for (int ky = 0; ky < 5; ++ky) {
            const float* rp = bc + (ty + ky) * 36 + qx * 4;
            float4 ra = *(const float4*)rp;
            float4 rb = *(const float4*)(rp + 4);
            float row[8] = {ra.x, ra.y, ra.z, ra.w, rb.x, rb.y, rb.z, rb.w};
#pragma unroll
            for (int kx = 0; kx < 5; ++kx) {
                float4 wA = *(const float4*)(wc + (ky * 5 + kx) * 32);
                float4 wB = *(const float4*)(wc + (ky * 5 + kx) * 32 + 4);
#pragma unroll
                for (int j = 0; j < 4; ++j) {
                    float v = row[kx + j];
                    acc[0][j] = fmaf(v, wA.x, acc[0][j]);
                    acc[1][j] = fmaf(v, wA.y, acc[1][j]);
                    acc[2][j] = fmaf(v, wA.z, acc[2][j]);
                    acc[3][j] = fmaf(v, wA.w, acc[3][j]);
                    acc[4][j] = fmaf(v, wB.x, acc[4][j]);
                    acc[5][j] = fmaf(v, wB.y, acc[5][j]);
                    acc[6][j] = fmaf(v, wB.z, acc[6][j]);
                    acc[7][j] = fmaf(v, wB.w, acc[7][j]);
                }
            }
        }
    }

    int pix = (by * 8 + ty) * HW + bx * 32 + qx * 4;
#pragma unroll
    for (int o = 0; o < 8; ++o) {
        int oc = og * 8 + o;
        float sc = W[SC1_OFF + oc], sh = W[SH1_OFF + oc];
        float4 r;
        r.x = fmaxf(fmaf(acc[o][0], sc, sh), 0.f);
        r.y = fmaxf(fmaf(acc[o][1], sc, sh), 0.f);
        r.z = fmaxf(fmaf(acc[o][2], sc, sh), 0.f);
        r.w = fmaxf(fmaf(acc[o][3], sc, sh), 0.f);
        *(float4*)&h1[oc * PLANE + pix] = r;
    }
}

// ---------------- conv2: 32 -> 8, 5x5, BN+ReLU ----------------
// 256 thr = 64 quad slots x 4 input-channel groups of 8; partial sums
// reduced through LDS (combine order cg0+cg1+cg2+cg3, sequential).
__global__ __launch_bounds__(256, 2) void conv2_kernel(
    const float* __restrict__ h1, const float* __restrict__ W,
    float* __restrict__ h2)
{
    __shared__ __align__(16) float lds[13824];   // tile [32][12][36]; later partials
    int tid = threadIdx.x;
    int cg = tid >> 6;            // input-channel group 0..3 (= wave id)
    int slot = tid & 63;
    int qx = slot & 7, ty = slot >> 3;
    int bx = blockIdx.x % 12, by = blockIdx.x / 12;
    int x0 = bx * 32 - 2, y0 = by * 8 - 2;

    int p0 = tid;
    int py0 = p0 / 36, px0 = p0 % 36;
    int gy0 = y0 + py0, gx0 = x0 + px0;
    bool ok0 = ((unsigned)gy0 < (unsigned)HW) && ((unsigned)gx0 < (unsigned)HW);
    int gofs0 = ok0 ? (gy0 * HW + gx0) : 0;

    int p1 = tid + 256;
    bool has1 = (p1 < 432);
    int py1 = p1 / 36, px1 = p1 % 36;
    int gy1 = y0 + py1, gx1 = x0 + px1;
    bool ok1 = has1 && ((unsigned)gy1 < (unsigned)HW) && ((unsigned)gx1 < (unsigned)HW);
    int gofs1 = ok1 ? (gy1 * HW + gx1) : 0;

#pragma unroll 4
    for (int c = 0; c < 32; ++c) {
        float v = h1[c * PLANE + gofs0];
        lds[c * 432 + p0] = ok0 ? v : 0.f;
    }
    if (has1) {
#pragma unroll 4
        for (int c = 0; c < 32; ++c) {
            float v = h1[c * PLANE + gofs1];
            lds[c * 432 + p1] = ok1 ? v : 0.f;
        }
    }
    __syncthreads();

    float acc[8][4];
#pragma unroll
    for (int o = 0; o < 8; ++o)
#pragma unroll
        for (int j = 0; j < 4; ++j) acc[o][j] = 0.f;

    const float* wb = W + WT2_OFF;   // [c*25+tap][8o]
#pragma unroll 1
    for (int cc = 0; cc < 8; ++cc) {
        int c = cg * 8 + cc;
        const float* bc = lds + c * 432;
        const float* wc = wb + c * 200;
#pragma unroll
        for (int ky = 0; ky < 5; ++ky) {
            const float* rp = bc + (ty + ky) * 36 + qx * 4;
            float4 ra = *(const float4*)rp;
            float4 rb = *(const float4*)(rp + 4);
            float row[8] = {ra.x, ra.y, ra.z, ra.w, rb.x, rb.y, rb.z, rb.w};
#pragma unroll
            for (int kx = 0; kx < 5; ++kx) {
                float4 wA = *(const float4*)(wc + (ky * 5 + kx) * 8);
                float4 wB = *(const float4*)(wc + (ky * 5 + kx) * 8 + 4);
#pragma unroll
                for (int j = 0; j < 4; ++j) {
                    float v = row[kx + j];
                    acc[0][j] = fmaf(v, wA.x, acc[0][j]);
                    acc[1][j] = fmaf(v, wA.y, acc[1][j]);
                    acc[2][j] = fmaf(v, wA.z, acc[2][j]);
                    acc[3][j] = fmaf(v, wA.w, acc[3][j]);
                    acc[4][j] = fmaf(v, wB.x, acc[4][j]);
                    acc[5][j] = fmaf(v, wB.y, acc[5][j]);
                    acc[6][j] = fmaf(v, wB.z, acc[6][j]);
                    acc[7][j] = fmaf(v, wB.w, acc[7][j]);
                }
            }
        }
    }
    __syncthreads();   // tile reads done; safe to overwrite with partials

    if (cg > 0) {
        float* pp = lds + ((cg - 1) * 64 + slot) * 36;   // stride 36 floats: conflict-free
#pragma unroll
        for (int o = 0; o < 8; ++o)
            *(float4*)(pp + o * 4) = make_float4(acc[o][0], acc[o][1], acc[o][2], acc[o][3]);
    }
    __syncthreads();

    if (cg == 0) {
#pragma unroll
        for (int g = 0; g < 3; ++g) {
            const float* pp = lds + (g * 64 + slot) * 36;
#pragma unroll
            for (int o = 0; o < 8; ++o) {
                float4 t = *(const float4*)(pp + o * 4);
                acc[o][0] += t.x; acc[o][1] += t.y;
                acc[o][2] += t.z; acc[o][3] += t.w;
            }
        }
        int pix = (by * 8 + ty) * HW + bx * 32 + qx * 4;
#pragma unroll
        for (int o = 0; o < 8; ++o) {
            float sc = W[SC2_OFF + o], sh = W[SH2_OFF + o];
            float4 r;
            r.x = fmaxf(fmaf(acc[o][0], sc, sh), 0.f);
            r.y = fmaxf(fmaf(acc[o][1], sc, sh), 0.f);
            r.z = fmaxf(fmaf(acc[o][2], sc, sh), 0.f);
            r.w = fmaxf(fmaf(acc[o][3], sc, sh), 0.f);
            *(float4*)&h2[o * PLANE + pix] = r;
        }
    }
}

// ---------------- conv3: 8 -> 1, 5x5, BN + sigmoid + floor -> depth ----------------
__global__ __launch_bounds__(256) void conv3_kernel(
    const float* __restrict__ h2, const float* __restrict__ W,
    int* __restrict__ depth)
{
    __shared__ float tile[8][12][36];
    int tid = threadIdx.x;
    int tx = tid & 31, ty = tid >> 5;
    int bx = blockIdx.x % 12, by = blockIdx.x / 12;
    int x0 = bx * 32 - 2, y0 = by * 8 - 2;

    for (int p = tid; p < 432; p += 256) {
        int py = p / 36, px = p % 36;
        int gy = y0 + py, gx = x0 + px;
        bool ok = ((unsigned)gy < (unsigned)HW) && ((unsigned)gx < (unsigned)HW);
        int gofs = ok ? (gy * HW + gx) : 0;
#pragma unroll
        for (int c = 0; c < 8; ++c) {
            float v = h2[c * PLANE + gofs];
            tile[c][py][px] = ok ? v : 0.f;
        }
    }
    __syncthreads();

    float a = 0.f;
#pragma unroll 1
    for (int c = 0; c < 8; ++c) {
#pragma unroll
        for (int ky = 0; ky < 5; ++ky) {
#pragma unroll
            for (int kx = 0; kx < 5; ++kx) {
                a = fmaf(tile[c][ty + ky][tx + kx], W[W3_OFF + (c * 5 + ky) * 5 + kx], a);
            }
        }
    }
    float y = fmaf(a, W[SC3_OFF], W[SH3_OFF]);
    float s = 1.f / (1.f + expf(-y));
    int d = (int)floorf(s * (16.f - 1e-5f));

    int gy = by * 8 + ty, gx = bx * 32 + tx;
    depth[gy * HW + gx] = d;
}

// ---------------- final: sparse 3d conv gather + divide + albedo ----------------
__global__ __launch_bounds__(256) void final_kernel(
    const float* __restrict__ light, const float* __restrict__ albedo,
    const float* __restrict__ W, const float* __restrict__ fb,
    float* __restrict__ out)
{
    __shared__ float fw[5488];
    __shared__ float ltile[3][14][38];
    __shared__ int   dtile[14][38];

    int tid = threadIdx.x;
    int tx = tid & 31, ty = tid >> 5;
    int bx = blockIdx.x % 12, by = blockIdx.x / 12;
    int x0 = bx * 32 - 3, y0 = by * 8 - 3;

    for (int i = tid; i < 5488; i += 256) fw[i] = W[FWT_OFF + i];

    const int* dmap = ((const int*)W) + DEPTH_OFF;
    for (int p = tid; p < 14 * 38; p += 256) {
        int py = p / 38, px = p % 38;
        int gy = y0 + py, gx = x0 + px;
        bool ok = ((unsigned)gy < (unsigned)HW) && ((unsigned)gx < (unsigned)HW);
        int gofs = ok ? (gy * HW + gx) : 0;
        int dv = dmap[gofs];
        dtile[py][px] = ok ? dv : -1000;
#pragma unroll
        for (int c = 0; c < 3; ++c) {
            float lv = light[c * PLANE + gofs];
            ltile[c][py][px] = ok ? lv : 0.f;
        }
    }
    __syncthreads();

    int d0 = dtile[ty + 3][tx + 3];
    float a0 = fb[0], a1 = fb[1], a2 = fb[2], a3 = fb[3];
    const float4* fw4 = (const float4*)fw;

#pragma unroll 1
    for (int dy = 0; dy < 7; ++dy) {
#pragma unroll
        for (int dx = 0; dx < 7; ++dx) {
            int dd = dtile[ty + dy][tx + dx];
            int dz = dd - d0 + 3;
            if ((unsigned)dz < 7u) {
                int s = (dz * 7 + dy) * 7 + dx;
                float4 w0 = fw4[s * 4 + 0];
                float4 w1 = fw4[s * 4 + 1];
                float4 w2 = fw4[s * 4 + 2];
                float4 w3 = fw4[s * 4 + 3];
                float l0 = ltile[0][ty + dy][tx + dx];
                float l1 = ltile[1][ty + dy][tx + dx];
                float l2 = ltile[2][ty + dy][tx + dx];
                a0 += l0 * w0.x + l1 * w1.x + l2 * w2.x + w3.x;
                a1 += l0 * w0.y + l1 * w1.y + l2 * w2.y + w3.y;
                a2 += l0 * w0.z + l1 * w1.z + l2 * w2.z + w3.z;
                a3 += l0 * w0.w + l1 * w1.w + l2 * w2.w + w3.w;
            }
        }
    }

    int gy = by * 8 + ty, gx = bx * 32 + tx;
    int pix = gy * HW + gx;
    out[0 * PLANE + pix] = a0 / a3 * albedo[0 * PLANE + pix];
    out[1 * PLANE + pix] = a1 / a3 * albedo[1 * PLANE + pix];
    out[2 * PLANE + pix] = a2 / a3 * albedo[2 * PLANE + pix];
}

extern "C" void kernel_launch(void* const* d_in, const int* in_sizes, int n_in,
                              void* d_out, int out_size, void* d_ws, size_t ws_size,
                              hipStream_t stream) {
    const float* light     = (const float*)d_in[0];
    const float* albedo    = (const float*)d_in[1];
    const float* normals   = (const float*)d_in[2];
    const float* c1_w = (const float*)d_in[4];
    const float* c1_b = (const float*)d_in[5];
    const float* bn1_g = (const float*)d_in[6];
    const float* bn1_b = (const float*)d_in[7];
    const float* bn1_m = (const float*)d_in[8];
    const float* bn1_v = (const float*)d_in[9];
    const float* c2_w = (const float*)d_in[10];
    const float* c2_b = (const float*)d_in[11];
    const float* bn2_g = (const float*)d_in[12];
    const float* bn2_b = (const float*)d_in[13];
    const float* bn2_m = (const float*)d_in[14];
    const float* bn2_v = (const float*)d_in[15];
    const float* c3_w = (const float*)d_in[16];
    const float* c3_b = (const float*)d_in[17];
    const float* bn3_g = (const float*)d_in[18];
    const float* bn3_b = (const float*)d_in[19];
    const float* bn3_m = (const float*)d_in[20];
    const float* bn3_v = (const float*)d_in[21];
    const float* f_w = (const float*)d_in[22];
    const float* f_b = (const float*)d_in[23];

    float* W = (float*)d_ws;
    float* h1 = W + H1_OFF;
    float* h2 = W + H2_OFF;
    int* depth = ((int*)d_ws) + DEPTH_OFF;
    float* out = (float*)d_out;

    hipLaunchKernelGGL(prep_kernel, dim3(16), dim3(256), 0, stream,
                       c1_w, c1_b, bn1_g, bn1_b, bn1_m, bn1_v,
                       c2_w, c2_b, bn2_g, bn2_b, bn2_m, bn2_v,
                       c3_w, c3_b, bn3_g, bn3_b, bn3_m, bn3_v,
                       f_w, W);
    hipLaunchKernelGGL(conv1_kernel, dim3(576), dim3(256), 0, stream,
                       light, albedo, normals, W, h1);
    hipLaunchKernelGGL(conv2_kernel, dim3(576), dim3(256), 0, stream,
                       h1, W, h2);
    hipLaunchKernelGGL(conv3_kernel, dim3(576), dim3(256), 0, stream,
                       h2, W, depth);
    hipLaunchKernelGGL(final_kernel, dim3(576), dim3(256), 0, stream,
                       light, albedo, W, f_b, out);
}